// Round 11
// baseline (476.385 us; speedup 1.0000x reference)
//
#include <hip/hip_runtime.h>
#include <math.h>

#define FD 128
#define CLS 40
#define BN_EPS 1e-5f
#define AS_STRIDE 136   // ushort stride: 272 B rows, 16B-aligned, 2-way bank aliasing only
// TM=64, single-bf16 B panels (R9). R11: agg fused as phase-0 of layer kernels
// (gathers straight into As LDS; ht/gate ping-pong buffers avoid RAW race).

typedef short short8 __attribute__((ext_vector_type(8)));
typedef float floatx4 __attribute__((ext_vector_type(4)));
typedef unsigned short ushort4v __attribute__((ext_vector_type(4)));
typedef unsigned short u16;
typedef unsigned int u32;

__device__ __forceinline__ u16 bf16_of(float v) {
    unsigned int u = __float_as_uint(v);
    unsigned int r = u + 0x7FFFu + ((u >> 16) & 1u);   // RNE
    return (u16)(r >> 16);
}
__device__ __forceinline__ float bf16f(u16 h) {
    return __uint_as_float(((unsigned int)h) << 16);
}
__device__ __forceinline__ float blo(u32 v) { return __uint_as_float(v << 16); }
__device__ __forceinline__ float bhi(u32 v) { return __uint_as_float(v & 0xFFFF0000u); }
__device__ __forceinline__ float hswish(float x) {
    return x * fminf(fmaxf(x + 3.0f, 0.0f), 6.0f) * (1.0f / 6.0f);
}

// ---------------------------------------------------------------------------
// CSR build: hist(+rank) -> 3-pass parallel exclusive scan -> rank-scatter
// ---------------------------------------------------------------------------
__global__ void hist_kernel(const int* __restrict__ dst, int* __restrict__ cnt,
                            int* __restrict__ rank, int E) {
    int e = blockIdx.x * 256 + threadIdx.x;
    if (e < E) rank[e] = atomicAdd(&cnt[dst[e]], 1);
}

__global__ __launch_bounds__(256) void scan_p1(const int* __restrict__ cnt,
                                               int* __restrict__ bsum, int Nn) {
    const int t = threadIdx.x, b = blockIdx.x;
    int i = b * 256 + t;
    int v = (i < Nn) ? cnt[i] : 0;
    #pragma unroll
    for (int o = 32; o; o >>= 1) v += __shfl_xor(v, o);
    __shared__ int ws[4];
    if ((t & 63) == 0) ws[t >> 6] = v;
    __syncthreads();
    if (t == 0) bsum[b] = ws[0] + ws[1] + ws[2] + ws[3];
}

__global__ __launch_bounds__(256) void scan_p2(int* __restrict__ bsum, int NB,
                                               int* __restrict__ offs, int Nn) {
    __shared__ int wsum[4];
    __shared__ int run_s;
    const int t = threadIdx.x, lane = t & 63, wid = t >> 6;
    if (t == 0) run_s = 0;
    __syncthreads();
    for (int base = 0; base < NB; base += 256) {
        int i = base + t;
        int v = (i < NB) ? bsum[i] : 0;
        int x = v;
        #pragma unroll
        for (int o = 1; o < 64; o <<= 1) {
            int y = __shfl_up(x, o);
            if (lane >= o) x += y;
        }
        if (lane == 63) wsum[wid] = x;
        __syncthreads();
        int pre = run_s;
        #pragma unroll
        for (int w = 0; w < 4; ++w) { if (w < wid) pre += wsum[w]; }
        if (i < NB) bsum[i] = pre + x - v;
        __syncthreads();
        if (t == 0) run_s += wsum[0] + wsum[1] + wsum[2] + wsum[3];
        __syncthreads();
    }
    if (t == 0) offs[Nn] = run_s;
}

__global__ __launch_bounds__(256) void scan_p3(const int* __restrict__ cnt,
                                               const int* __restrict__ bsum,
                                               int* __restrict__ offs, int Nn) {
    __shared__ int wsum[4];
    const int t = threadIdx.x, b = blockIdx.x, lane = t & 63, wid = t >> 6;
    int i = b * 256 + t;
    int v = (i < Nn) ? cnt[i] : 0;
    int x = v;
    #pragma unroll
    for (int o = 1; o < 64; o <<= 1) {
        int y = __shfl_up(x, o);
        if (lane >= o) x += y;
    }
    if (lane == 63) wsum[wid] = x;
    __syncthreads();
    int pre = bsum[b];
    #pragma unroll
    for (int w = 0; w < 4; ++w) { if (w < wid) pre += wsum[w]; }
    if (i < Nn) offs[i] = pre + x - v;
}

__global__ void scatter_kernel(const int* __restrict__ src, const int* __restrict__ dst,
                               const int* __restrict__ offs, const int* __restrict__ rank,
                               int* __restrict__ col, int E) {
    int e = blockIdx.x * 256 + threadIdx.x;
    if (e < E) col[offs[dst[e]] + rank[e]] = src[e];
}

// ---------------------------------------------------------------------------
// Weight prep: square W[k][n] -> bf16 transposed [n][k] (32768-short slots,
// hi only). Wp2 padded [48][128]. Wg panels [16][128].
// ---------------------------------------------------------------------------
__global__ void prep_weights(const float* __restrict__ Wt, const float* __restrict__ W1,
                             const float* __restrict__ W2, const float* __restrict__ Wp1,
                             const float* __restrict__ Wp2, const float* __restrict__ Wg,
                             u16* __restrict__ wbuf, int L) {
    const int m = blockIdx.y;
    const int id = blockIdx.x * 256 + threadIdx.x;
    const int nsq = 3 * L + 1;
    if (m < nsq) {
        u16* base = wbuf + (size_t)m * 32768;
        const float* src = (m < L) ? Wt + m * 16384
                         : (m < 2 * L) ? W1 + (m - L) * 16384
                         : (m < 3 * L) ? W2 + (m - 2 * L) * 16384
                         : Wp1;
        int n = id >> 7, k = id & 127;
        base[n * 128 + k] = bf16_of(src[k * 128 + n]);
    } else if (m == nsq) {               // Wp2
        if (id >= 48 * 128) return;
        u16* base = wbuf + (size_t)m * 32768;
        int n = id >> 7, k = id & 127;
        base[n * 128 + k] = bf16_of((n < CLS) ? Wp2[k * CLS + n] : 0.f);
    } else {                             // Wg panel
        int gi = m - (nsq + 1);
        if (id >= 2048) return;
        u16* base = wbuf + (size_t)(nsq + 1) * 32768 + (size_t)gi * 4096;
        base[id] = bf16_of((id < 128) ? Wg[gi * 128 + id] : 0.f);
    }
}

// ---------------------------------------------------------------------------
// GEMM building blocks. Block tile 64 rows x 128 cols, K=128, 4 waves.
// COLUMN-split: wave w owns cols [32w, 32w+32); 8 single-bf16 B-fragments in
// registers for the whole GEMM -> 8 MFMAs per B-load, no re-fetch.
// ---------------------------------------------------------------------------
__device__ __forceinline__ void stage_f32(const float* __restrict__ A, int m0, int M,
                                          u16* As, int t) {
    #pragma unroll
    for (int i = 0; i < 8; ++i) {
        int id = i * 256 + t;
        int row = id >> 5, c4 = id & 31;
        float4 v = make_float4(0.f, 0.f, 0.f, 0.f);
        if (m0 + row < M) v = ((const float4*)A)[(size_t)(m0 + row) * 32 + c4];
        ushort4v hh = {bf16_of(v.x), bf16_of(v.y), bf16_of(v.z), bf16_of(v.w)};
        *(ushort4v*)(&As[row * AS_STRIDE + c4 * 4]) = hh;
    }
}

struct Bfrags { short8 h[2][4]; };   // [ct][kc], 32 VGPRs (single bf16)

__device__ __forceinline__ void load_B(const u16* __restrict__ Bh,
                                       int ct0, int l16, int quad, Bfrags& f) {
    #pragma unroll
    for (int c = 0; c < 2; ++c)
        #pragma unroll
        for (int kc = 0; kc < 4; ++kc) {
            int boff = ((ct0 + c) * 16 + l16) * 128 + kc * 32 + quad * 8;
            f.h[c][kc] = *(const short8*)(&Bh[boff]);
        }
}

__device__ __forceinline__ void gemm_ct2(const u16* As, const Bfrags& f, int l16, int quad,
                                         floatx4 (&acc)[4][2]) {
    #pragma unroll
    for (int kc = 0; kc < 4; ++kc) {
        short8 a[4];
        #pragma unroll
        for (int rt = 0; rt < 4; ++rt)
            a[rt] = *(const short8*)(&As[(rt * 16 + l16) * AS_STRIDE + kc * 32 + quad * 8]);
        #pragma unroll
        for (int rt = 0; rt < 4; ++rt)
            #pragma unroll
            for (int c = 0; c < 2; ++c)
                acc[rt][c] = __builtin_amdgcn_mfma_f32_16x16x32_bf16(a[rt], f.h[c][kc], acc[rt][c], 0, 0, 0);
    }
}

#define ZERO_ACC(acc) { _Pragma("unroll") for (int rt = 0; rt < 4; ++rt) \
    { acc[rt][0] = (floatx4){0.f,0.f,0.f,0.f}; acc[rt][1] = (floatx4){0.f,0.f,0.f,0.f}; } }

// gate panel (16x128, only col 0 nonzero) on wave 0; writes gate rows
__device__ __forceinline__ void gate_panel(const u16* As, const u16* __restrict__ Gh,
                                           const float* __restrict__ bg,
                                           float* __restrict__ gate,
                                           int m0, int M, int l16, int quad) {
    floatx4 gacc[4];
    #pragma unroll
    for (int rt = 0; rt < 4; ++rt) gacc[rt] = (floatx4){0.f, 0.f, 0.f, 0.f};
    #pragma unroll
    for (int kc = 0; kc < 4; ++kc) {
        int boff = l16 * 128 + kc * 32 + quad * 8;
        short8 gh = *(const short8*)(&Gh[boff]);
        #pragma unroll
        for (int rt = 0; rt < 4; ++rt) {
            short8 a = *(const short8*)(&As[(rt * 16 + l16) * AS_STRIDE + kc * 32 + quad * 8]);
            gacc[rt] = __builtin_amdgcn_mfma_f32_16x16x32_bf16(a, gh, gacc[rt], 0, 0, 0);
        }
    }
    if (l16 == 0) {
        float b0 = bg[0];
        #pragma unroll
        for (int rt = 0; rt < 4; ++rt)
            #pragma unroll
            for (int reg = 0; reg < 4; ++reg) {
                int row = m0 + rt * 16 + quad * 4 + reg;
                if (row < M) gate[row] = gacc[rt][reg] + b0;
            }
    }
}

// ---------------------------------------------------------------------------
// Fused agg phase: wave w aggregates its 16 nodes (serial, 8-unrolled gather,
// max-free softmax shifted by self-gate) straight into As rows (bf16 packed).
// Numerically identical to the standalone agg + restage path.
// ---------------------------------------------------------------------------
__device__ __forceinline__ void agg_rows(const float* __restrict__ gate,
                                         const u32* __restrict__ ht32,
                                         const int* __restrict__ offs,
                                         const int* __restrict__ col,
                                         u16* As, int m0, int M, int w, int lane) {
    for (int s = 0; s < 16; ++s) {
        int row = w * 16 + s;
        int n = m0 + row;
        u32 packed = 0;
        if (n < M) {
            int beg = offs[n], end = offs[n + 1];
            float gs = gate[n];
            float denom0 = 1.0f, denom1 = 0.f;       // self: exp(0)=1
            u32 sv = ht32[(size_t)n * 64 + lane];
            float a0 = blo(sv), a1 = bhi(sv);
            float b0 = 0.f, b1 = 0.f;
            int e = beg;
            for (; e + 8 <= end; e += 8) {
                int c[8];
                #pragma unroll
                for (int j = 0; j < 8; ++j) c[j] = col[e + j];
                float g[8];
                #pragma unroll
                for (int j = 0; j < 8; ++j) g[j] = gate[c[j]];
                u32 v[8];
                #pragma unroll
                for (int j = 0; j < 8; ++j) v[j] = ht32[(size_t)c[j] * 64 + lane];
                float wj[8];
                #pragma unroll
                for (int j = 0; j < 8; ++j) wj[j] = __expf(g[j] - gs);
                denom0 += (wj[0] + wj[1]) + (wj[2] + wj[3]);
                denom1 += (wj[4] + wj[5]) + (wj[6] + wj[7]);
                #pragma unroll
                for (int j = 0; j < 4; ++j) {
                    a0 += wj[j] * blo(v[j]);
                    a1 += wj[j] * bhi(v[j]);
                }
                #pragma unroll
                for (int j = 4; j < 8; ++j) {
                    b0 += wj[j] * blo(v[j]);
                    b1 += wj[j] * bhi(v[j]);
                }
            }
            for (; e < end; ++e) {
                int c = col[e];
                float wj = __expf(gate[c] - gs);
                u32 v = ht32[(size_t)c * 64 + lane];
                denom0 += wj;
                a0 += wj * blo(v);
                a1 += wj * bhi(v);
            }
            float inv = 1.0f / (denom0 + denom1);
            packed = (u32)bf16_of((a0 + b0) * inv) | ((u32)bf16_of((a1 + b1) * inv) << 16);
        }
        *(u32*)(&As[row * AS_STRIDE + lane * 2]) = packed;
    }
}

// ---------------------------------------------------------------------------
// Layer-0 entry: ht(bf16) = x @ Wt + bt ; gate = x @ Wg + bg   (x is f32)
// ---------------------------------------------------------------------------
__global__ __launch_bounds__(256, 3) void gemm_gate_kernel(
    const float* __restrict__ Af,
    const u16* __restrict__ Gh, const float* __restrict__ bg,
    const u16* __restrict__ Bh, const float* __restrict__ bt,
    u16* __restrict__ ht, float* __restrict__ gate, int M) {
    __shared__ __align__(16) u16 As[64 * AS_STRIDE];
    const int t = threadIdx.x, m0 = blockIdx.x * 64;
    const int w = t >> 6, lane = t & 63, l16 = lane & 15, quad = lane >> 4, ct0 = w * 2;
    Bfrags f;
    load_B(Bh, ct0, l16, quad, f);      // in flight during staging
    stage_f32(Af, m0, M, As, t);
    __syncthreads();
    floatx4 acc[4][2];
    ZERO_ACC(acc);
    gemm_ct2(As, f, l16, quad, acc);
    if (w == 0) gate_panel(As, Gh, bg, gate, m0, M, l16, quad);
    #pragma unroll
    for (int c = 0; c < 2; ++c) {
        int cc = (ct0 + c) * 16 + l16;
        float b = bt[cc];
        #pragma unroll
        for (int rt = 0; rt < 4; ++rt)
            #pragma unroll
            for (int reg = 0; reg < 4; ++reg) {
                int row = m0 + rt * 16 + quad * 4 + reg;
                if (row < M) ht[(size_t)row * 128 + cc] = bf16_of(acc[rt][c][reg] + b);
            }
    }
}

// ---------------------------------------------------------------------------
// Mid-layer mega kernel: [fused agg of own 64 rows] -> W1/BN/hswish ->
// W2/hswish -> next layer's ht/gate. Reads ht_in/gate_in, writes ht_out/
// gate_out (ping-pong buffers — blocks race otherwise).
// ---------------------------------------------------------------------------
__global__ __launch_bounds__(256, 3) void layer_mid_kernel(
    const float* __restrict__ gate_in, const u32* __restrict__ ht_in,
    const int* __restrict__ offs, const int* __restrict__ col,
    const u16* __restrict__ B1h, const float* __restrict__ b1,
    const float* __restrict__ bng, const float* __restrict__ bnb,
    const float* __restrict__ bnm, const float* __restrict__ bnv,
    const u16* __restrict__ B2h, const float* __restrict__ b2,
    const u16* __restrict__ Wth, const float* __restrict__ bt,
    const u16* __restrict__ Gh, const float* __restrict__ bg,
    u16* __restrict__ ht_out, float* __restrict__ gate_out, int M) {
    __shared__ __align__(16) u16 As[64 * AS_STRIDE];
    __shared__ __align__(16) u16 Zs[64 * AS_STRIDE];
    const int t = threadIdx.x, m0 = blockIdx.x * 64;
    const int w = t >> 6, lane = t & 63, l16 = lane & 15, quad = lane >> 4, ct0 = w * 2;
    agg_rows(gate_in, ht_in, offs, col, As, m0, M, w, lane);   // phase 0
    Bfrags f;
    load_B(B1h, ct0, l16, quad, f);     // in flight across the barrier
    __syncthreads();
    floatx4 acc[4][2];
    ZERO_ACC(acc);
    gemm_ct2(As, f, l16, quad, acc);
    // z = hswish(BN(acc+b1)) -> Zs
    #pragma unroll
    for (int c = 0; c < 2; ++c) {
        int cc = (ct0 + c) * 16 + l16;
        float sc = bng[cc] * rsqrtf(bnv[cc] + BN_EPS);
        float sh = bnb[cc] - bnm[cc] * sc;
        float bb = b1[cc];
        #pragma unroll
        for (int rt = 0; rt < 4; ++rt)
            #pragma unroll
            for (int reg = 0; reg < 4; ++reg) {
                int r = rt * 16 + quad * 4 + reg;
                Zs[r * AS_STRIDE + cc] = bf16_of(hswish((acc[rt][c][reg] + bb) * sc + sh));
            }
    }
    load_B(B2h, ct0, l16, quad, f);
    __syncthreads();            // Zs complete; As reads complete -> As reusable
    ZERO_ACC(acc);
    gemm_ct2(Zs, f, l16, quad, acc);
    // h = hswish(acc+b2) -> As (bf16)
    #pragma unroll
    for (int c = 0; c < 2; ++c) {
        int cc = (ct0 + c) * 16 + l16;
        float b = b2[cc];
        #pragma unroll
        for (int rt = 0; rt < 4; ++rt)
            #pragma unroll
            for (int reg = 0; reg < 4; ++reg) {
                int r = rt * 16 + quad * 4 + reg;
                As[r * AS_STRIDE + cc] = bf16_of(hswish(acc[rt][c][reg] + b));
            }
    }
    load_B(Wth, ct0, l16, quad, f);
    __syncthreads();            // h tile complete in As
    ZERO_ACC(acc);
    gemm_ct2(As, f, l16, quad, acc);
    if (w == 0) gate_panel(As, Gh, bg, gate_out, m0, M, l16, quad);
    #pragma unroll
    for (int c = 0; c < 2; ++c) {
        int cc = (ct0 + c) * 16 + l16;
        float b = bt[cc];
        #pragma unroll
        for (int rt = 0; rt < 4; ++rt)
            #pragma unroll
            for (int reg = 0; reg < 4; ++reg) {
                int row = m0 + rt * 16 + quad * 4 + reg;
                if (row < M) ht_out[(size_t)row * 128 + cc] = bf16_of(acc[rt][c][reg] + b);
            }
    }
}

// ---------------------------------------------------------------------------
// Final-layer mega kernel: [fused agg] -> h -> head: z' = hswish(h@Wp1+bp1),
// logits = z'@Wp2+bp2, out = log_softmax(logits).
// ---------------------------------------------------------------------------
__global__ __launch_bounds__(256, 3) void layer_final_kernel(
    const float* __restrict__ gate_in, const u32* __restrict__ ht_in,
    const int* __restrict__ offs, const int* __restrict__ col,
    const u16* __restrict__ B1h, const float* __restrict__ b1,
    const float* __restrict__ bng, const float* __restrict__ bnb,
    const float* __restrict__ bnm, const float* __restrict__ bnv,
    const u16* __restrict__ B2h, const float* __restrict__ b2,
    const u16* __restrict__ P1h, const float* __restrict__ bp1,
    const u16* __restrict__ P2h, const float* __restrict__ bp2,
    float* __restrict__ out, int M) {
    __shared__ __align__(16) u16 As[64 * AS_STRIDE];
    __shared__ __align__(16) u16 Zs[64 * AS_STRIDE];
    const int t = threadIdx.x, m0 = blockIdx.x * 64;
    const int w = t >> 6, lane = t & 63, l16 = lane & 15, quad = lane >> 4, ct0 = w * 2;
    agg_rows(gate_in, ht_in, offs, col, As, m0, M, w, lane);   // phase 0
    Bfrags f;
    load_B(B1h, ct0, l16, quad, f);
    __syncthreads();
    floatx4 acc[4][2];
    ZERO_ACC(acc);
    gemm_ct2(As, f, l16, quad, acc);
    #pragma unroll
    for (int c = 0; c < 2; ++c) {
        int cc = (ct0 + c) * 16 + l16;
        float sc = bng[cc] * rsqrtf(bnv[cc] + BN_EPS);
        float sh = bnb[cc] - bnm[cc] * sc;
        float bb = b1[cc];
        #pragma unroll
        for (int rt = 0; rt < 4; ++rt)
            #pragma unroll
            for (int reg = 0; reg < 4; ++reg) {
                int r = rt * 16 + quad * 4 + reg;
                Zs[r * AS_STRIDE + cc] = bf16_of(hswish((acc[rt][c][reg] + bb) * sc + sh));
            }
    }
    load_B(B2h, ct0, l16, quad, f);
    __syncthreads();
    ZERO_ACC(acc);
    gemm_ct2(Zs, f, l16, quad, acc);
    // h = hswish(acc+b2) -> As
    #pragma unroll
    for (int c = 0; c < 2; ++c) {
        int cc = (ct0 + c) * 16 + l16;
        float b = b2[cc];
        #pragma unroll
        for (int rt = 0; rt < 4; ++rt)
            #pragma unroll
            for (int reg = 0; reg < 4; ++reg) {
                int r = rt * 16 + quad * 4 + reg;
                As[r * AS_STRIDE + cc] = bf16_of(hswish(acc[rt][c][reg] + b));
            }
    }
    load_B(P1h, ct0, l16, quad, f);
    __syncthreads();
    ZERO_ACC(acc);
    gemm_ct2(As, f, l16, quad, acc);
    // z' = hswish(acc+bp1) -> Zs
    #pragma unroll
    for (int c = 0; c < 2; ++c) {
        int cc = (ct0 + c) * 16 + l16;
        float bb = bp1[cc];
        #pragma unroll
        for (int rt = 0; rt < 4; ++rt)
            #pragma unroll
            for (int reg = 0; reg < 4; ++reg) {
                int r = rt * 16 + quad * 4 + reg;
                Zs[r * AS_STRIDE + cc] = bf16_of(hswish(acc[rt][c][reg] + bb));
            }
    }
    __syncthreads();
    // head GEMM2 row-split: wave w owns rows [16w,16w+16), all 3 col-tiles
    const int wr0 = w * 16;
    floatx4 acc2[3];
    #pragma unroll
    for (int ct = 0; ct < 3; ++ct) acc2[ct] = (floatx4){0.f, 0.f, 0.f, 0.f};
    #pragma unroll
    for (int kc = 0; kc < 4; ++kc) {
        short8 a = *(const short8*)(&Zs[(wr0 + l16) * AS_STRIDE + kc * 32 + quad * 8]);
        #pragma unroll
        for (int ct = 0; ct < 3; ++ct) {
            int boff = (ct * 16 + l16) * 128 + kc * 32 + quad * 8;
            short8 bh = *(const short8*)(&P2h[boff]);
            acc2[ct] = __builtin_amdgcn_mfma_f32_16x16x32_bf16(a, bh, acc2[ct], 0, 0, 0);
        }
    }
    #pragma unroll
    for (int reg = 0; reg < 4; ++reg) {
        float v[3];
        #pragma unroll
        for (int ct = 0; ct < 3; ++ct) {
            int c = ct * 16 + l16;
            v[ct] = (c < CLS) ? acc2[ct][reg] + bp2[c] : -INFINITY;
        }
        float mx = fmaxf(fmaxf(v[0], v[1]), v[2]);
        #pragma unroll
        for (int o = 1; o < 16; o <<= 1) mx = fmaxf(mx, __shfl_xor(mx, o));
        float s = 0.f;
        #pragma unroll
        for (int ct = 0; ct < 3; ++ct) s += (v[ct] > -INFINITY) ? __expf(v[ct] - mx) : 0.f;
        #pragma unroll
        for (int o = 1; o < 16; o <<= 1) s += __shfl_xor(s, o);
        float lse = mx + __logf(s);
        int row = m0 + wr0 + quad * 4 + reg;
        if (row < M) {
            #pragma unroll
            for (int ct = 0; ct < 3; ++ct) {
                int c = ct * 16 + l16;
                if (c < CLS) out[(size_t)row * CLS + c] = v[ct] - lse;
            }
        }
    }
}

// ---------------------------------------------------------------------------
extern "C" void kernel_launch(void* const* d_in, const int* in_sizes, int n_in,
                              void* d_out, int out_size, void* d_ws, size_t ws_size,
                              hipStream_t stream) {
    const float* x   = (const float*)d_in[0];
    const int*   src = (const int*)d_in[1];
    const int*   dst = (const int*)d_in[2];
    const float* Wg  = (const float*)d_in[3];
    const float* bg  = (const float*)d_in[4];
    const float* Wt  = (const float*)d_in[5];
    const float* bt  = (const float*)d_in[6];
    const float* W1  = (const float*)d_in[7];
    const float* b1  = (const float*)d_in[8];
    const float* bng = (const float*)d_in[9];
    const float* bnb = (const float*)d_in[10];
    const float* bnm = (const float*)d_in[11];
    const float* bnv = (const float*)d_in[12];
    const float* W2  = (const float*)d_in[13];
    const float* b2  = (const float*)d_in[14];
    const float* Wp1 = (const float*)d_in[15];
    const float* bp1 = (const float*)d_in[16];
    const float* Wp2 = (const float*)d_in[17];
    const float* bp2 = (const float*)d_in[18];
    float* out = (float*)d_out;

    const int N = in_sizes[0] / FD;
    const int E = in_sizes[1];
    const int L = in_sizes[3] / FD;
    const int nsq = 3 * L + 1;
    const int NB = (N + 255) / 256;

    u16* ht0    = (u16*)d_ws;                          // N*128 bf16 (ping)
    u16* ht1    = ht0 + (size_t)N * FD;                // N*128 bf16 (pong)
    float* ga0  = (float*)(ht1 + (size_t)N * FD);      // N (ping)
    float* ga1  = ga0 + N;                             // N (pong)
    u16* wbuf   = (u16*)(ga1 + N);
    size_t wslots = (size_t)(nsq + 1) * 32768 + (size_t)L * 4096;
    int* counts = (int*)(wbuf + wslots);
    int* offs   = counts + N;
    int* rank   = offs + (N + 1);
    int* col    = rank + E;
    int* bsum   = col + E;

    // CSR build + weight prep (static inputs, ws re-poisoned each call)
    hipMemsetAsync(counts, 0, N * sizeof(int), stream);
    hist_kernel<<<(E + 255) / 256, 256, 0, stream>>>(dst, counts, rank, E);
    prep_weights<<<dim3(64, nsq + 1 + L), 256, 0, stream>>>(Wt, W1, W2, Wp1, Wp2, Wg, wbuf, L);
    scan_p1<<<NB, 256, 0, stream>>>(counts, bsum, N);
    scan_p2<<<1, 256, 0, stream>>>(bsum, NB, offs, N);
    scan_p3<<<NB, 256, 0, stream>>>(counts, bsum, offs, N);
    scatter_kernel<<<(E + 255) / 256, 256, 0, stream>>>(src, dst, offs, rank, col, E);

    const int grid_g = (N + 63) / 64;

    u16* gp0 = wbuf + (size_t)(nsq + 1) * 32768;
    u16* wt0 = wbuf;
    gemm_gate_kernel<<<grid_g, 256, 0, stream>>>(x, gp0, bg, wt0, bt, ht0, ga0, N);
    u16* ht_in = ht0; float* ga_in = ga0;
    u16* ht_nx = ht1; float* ga_nx = ga1;
    for (int i = 0; i < L; ++i) {
        u16* w1 = wbuf + (size_t)(L + i) * 32768;
        u16* w2 = wbuf + (size_t)(2 * L + i) * 32768;
        if (i < L - 1) {
            u16* wtn = wbuf + (size_t)(i + 1) * 32768;
            u16* gpn = wbuf + (size_t)(nsq + 1) * 32768 + (size_t)(i + 1) * 4096;
            layer_mid_kernel<<<grid_g, 256, 0, stream>>>(
                ga_in, (const u32*)ht_in, offs, col,
                w1, b1 + i * FD,
                bng + i * FD, bnb + i * FD, bnm + i * FD, bnv + i * FD,
                w2, b2 + i * FD,
                wtn, bt + (i + 1) * FD,
                gpn, bg + (i + 1),
                ht_nx, ga_nx, N);
            u16* tb = ht_in; ht_in = ht_nx; ht_nx = tb;
            float* tg = ga_in; ga_in = ga_nx; ga_nx = tg;
        } else {
            u16* wp1 = wbuf + (size_t)(3 * L) * 32768;
            u16* wp2 = wbuf + (size_t)nsq * 32768;
            layer_final_kernel<<<grid_g, 256, 0, stream>>>(
                ga_in, (const u32*)ht_in, offs, col,
                w1, b1 + i * FD,
                bng + i * FD, bnb + i * FD, bnm + i * FD, bnv + i * FD,
                w2, b2 + i * FD,
                wp1, bp1,
                wp2, bp2,
                out, N);
        }
    }
}

// Round 12
// 473.539 us; speedup vs baseline: 1.0060x; 1.0060x over previous
//
#include <hip/hip_runtime.h>
#include <math.h>

#define FD 128
#define CLS 40
#define BN_EPS 1e-5f
#define AS_STRIDE 136   // ushort stride: 272 B rows, 16B-aligned, 2-way bank aliasing only
// TM=64, single-bf16 B panels (R9). R12: standalone agg restored (R11's fused
// agg serialized the gather and regressed); edge softmax weights precomputed
// per layer into CSR order (same __expf operands -> bit-identical absmax).

typedef short short8 __attribute__((ext_vector_type(8)));
typedef float floatx4 __attribute__((ext_vector_type(4)));
typedef unsigned short ushort4v __attribute__((ext_vector_type(4)));
typedef unsigned short u16;
typedef unsigned int u32;

__device__ __forceinline__ u16 bf16_of(float v) {
    unsigned int u = __float_as_uint(v);
    unsigned int r = u + 0x7FFFu + ((u >> 16) & 1u);   // RNE
    return (u16)(r >> 16);
}
__device__ __forceinline__ float bf16f(u16 h) {
    return __uint_as_float(((unsigned int)h) << 16);
}
__device__ __forceinline__ float blo(u32 v) { return __uint_as_float(v << 16); }
__device__ __forceinline__ float bhi(u32 v) { return __uint_as_float(v & 0xFFFF0000u); }
__device__ __forceinline__ float hswish(float x) {
    return x * fminf(fmaxf(x + 3.0f, 0.0f), 6.0f) * (1.0f / 6.0f);
}

// ---------------------------------------------------------------------------
// CSR build: hist(+rank) -> 3-pass parallel exclusive scan -> rank-scatter
// ---------------------------------------------------------------------------
__global__ void hist_kernel(const int* __restrict__ dst, int* __restrict__ cnt,
                            int* __restrict__ rank, int E) {
    int e = blockIdx.x * 256 + threadIdx.x;
    if (e < E) rank[e] = atomicAdd(&cnt[dst[e]], 1);
}

__global__ __launch_bounds__(256) void scan_p1(const int* __restrict__ cnt,
                                               int* __restrict__ bsum, int Nn) {
    const int t = threadIdx.x, b = blockIdx.x;
    int i = b * 256 + t;
    int v = (i < Nn) ? cnt[i] : 0;
    #pragma unroll
    for (int o = 32; o; o >>= 1) v += __shfl_xor(v, o);
    __shared__ int ws[4];
    if ((t & 63) == 0) ws[t >> 6] = v;
    __syncthreads();
    if (t == 0) bsum[b] = ws[0] + ws[1] + ws[2] + ws[3];
}

__global__ __launch_bounds__(256) void scan_p2(int* __restrict__ bsum, int NB,
                                               int* __restrict__ offs, int Nn) {
    __shared__ int wsum[4];
    __shared__ int run_s;
    const int t = threadIdx.x, lane = t & 63, wid = t >> 6;
    if (t == 0) run_s = 0;
    __syncthreads();
    for (int base = 0; base < NB; base += 256) {
        int i = base + t;
        int v = (i < NB) ? bsum[i] : 0;
        int x = v;
        #pragma unroll
        for (int o = 1; o < 64; o <<= 1) {
            int y = __shfl_up(x, o);
            if (lane >= o) x += y;
        }
        if (lane == 63) wsum[wid] = x;
        __syncthreads();
        int pre = run_s;
        #pragma unroll
        for (int w = 0; w < 4; ++w) { if (w < wid) pre += wsum[w]; }
        if (i < NB) bsum[i] = pre + x - v;
        __syncthreads();
        if (t == 0) run_s += wsum[0] + wsum[1] + wsum[2] + wsum[3];
        __syncthreads();
    }
    if (t == 0) offs[Nn] = run_s;
}

__global__ __launch_bounds__(256) void scan_p3(const int* __restrict__ cnt,
                                               const int* __restrict__ bsum,
                                               int* __restrict__ offs, int Nn) {
    __shared__ int wsum[4];
    const int t = threadIdx.x, b = blockIdx.x, lane = t & 63, wid = t >> 6;
    int i = b * 256 + t;
    int v = (i < Nn) ? cnt[i] : 0;
    int x = v;
    #pragma unroll
    for (int o = 1; o < 64; o <<= 1) {
        int y = __shfl_up(x, o);
        if (lane >= o) x += y;
    }
    if (lane == 63) wsum[wid] = x;
    __syncthreads();
    int pre = bsum[b];
    #pragma unroll
    for (int w = 0; w < 4; ++w) { if (w < wid) pre += wsum[w]; }
    if (i < Nn) offs[i] = pre + x - v;
}

__global__ void scatter_kernel(const int* __restrict__ src, const int* __restrict__ dst,
                               const int* __restrict__ offs, const int* __restrict__ rank,
                               int* __restrict__ col, int E) {
    int e = blockIdx.x * 256 + threadIdx.x;
    if (e < E) col[offs[dst[e]] + rank[e]] = src[e];
}

// ---------------------------------------------------------------------------
// Per-layer edge softmax weight: w[csr_pos] = exp(gate[src] - gate[dst]).
// Edge-order traversal (coalesced src/dst/rank reads); gate is 200 KB ->
// L2-resident gathers, fully latency-hidden across 600k lanes. Removes the
// dependent gate-gather level from agg's critical loop. Bit-identical math.
// ---------------------------------------------------------------------------
__global__ void edge_w_kernel(const int* __restrict__ src, const int* __restrict__ dst,
                              const int* __restrict__ offs, const int* __restrict__ rank,
                              const float* __restrict__ gate, float* __restrict__ wcsr,
                              int E) {
    int e = blockIdx.x * 256 + threadIdx.x;
    if (e < E) {
        int d = dst[e];
        wcsr[offs[d] + rank[e]] = __expf(gate[src[e]] - gate[d]);
    }
}

// ---------------------------------------------------------------------------
// Weight prep: square W[k][n] -> bf16 transposed [n][k] (32768-short slots,
// hi only). Wp2 padded [48][128]. Wg panels [16][128].
// ---------------------------------------------------------------------------
__global__ void prep_weights(const float* __restrict__ Wt, const float* __restrict__ W1,
                             const float* __restrict__ W2, const float* __restrict__ Wp1,
                             const float* __restrict__ Wp2, const float* __restrict__ Wg,
                             u16* __restrict__ wbuf, int L) {
    const int m = blockIdx.y;
    const int id = blockIdx.x * 256 + threadIdx.x;
    const int nsq = 3 * L + 1;
    if (m < nsq) {
        u16* base = wbuf + (size_t)m * 32768;
        const float* src = (m < L) ? Wt + m * 16384
                         : (m < 2 * L) ? W1 + (m - L) * 16384
                         : (m < 3 * L) ? W2 + (m - 2 * L) * 16384
                         : Wp1;
        int n = id >> 7, k = id & 127;
        base[n * 128 + k] = bf16_of(src[k * 128 + n]);
    } else if (m == nsq) {               // Wp2
        if (id >= 48 * 128) return;
        u16* base = wbuf + (size_t)m * 32768;
        int n = id >> 7, k = id & 127;
        base[n * 128 + k] = bf16_of((n < CLS) ? Wp2[k * CLS + n] : 0.f);
    } else {                             // Wg panel
        int gi = m - (nsq + 1);
        if (id >= 2048) return;
        u16* base = wbuf + (size_t)(nsq + 1) * 32768 + (size_t)gi * 4096;
        base[id] = bf16_of((id < 128) ? Wg[gi * 128 + id] : 0.f);
    }
}

// ---------------------------------------------------------------------------
// GEMM building blocks. Block tile 64 rows x 128 cols, K=128, 4 waves.
// COLUMN-split: wave w owns cols [32w, 32w+32); 8 single-bf16 B-fragments in
// registers for the whole GEMM -> 8 MFMAs per B-load, no re-fetch.
// ---------------------------------------------------------------------------
__device__ __forceinline__ void stage_f32(const float* __restrict__ A, int m0, int M,
                                          u16* As, int t) {
    #pragma unroll
    for (int i = 0; i < 8; ++i) {
        int id = i * 256 + t;
        int row = id >> 5, c4 = id & 31;
        float4 v = make_float4(0.f, 0.f, 0.f, 0.f);
        if (m0 + row < M) v = ((const float4*)A)[(size_t)(m0 + row) * 32 + c4];
        ushort4v hh = {bf16_of(v.x), bf16_of(v.y), bf16_of(v.z), bf16_of(v.w)};
        *(ushort4v*)(&As[row * AS_STRIDE + c4 * 4]) = hh;
    }
}

__device__ __forceinline__ void stage_bf16(const u16* __restrict__ A, int m0, int M,
                                           u16* As, int t) {
    #pragma unroll
    for (int i = 0; i < 4; ++i) {
        int id = i * 256 + t;
        int row = id >> 4, c8 = id & 15;
        short8 v = {0, 0, 0, 0, 0, 0, 0, 0};
        if (m0 + row < M) v = ((const short8*)A)[(size_t)(m0 + row) * 16 + c8];
        *(short8*)(&As[row * AS_STRIDE + c8 * 8]) = v;
    }
}

struct Bfrags { short8 h[2][4]; };   // [ct][kc], 32 VGPRs (single bf16)

__device__ __forceinline__ void load_B(const u16* __restrict__ Bh,
                                       int ct0, int l16, int quad, Bfrags& f) {
    #pragma unroll
    for (int c = 0; c < 2; ++c)
        #pragma unroll
        for (int kc = 0; kc < 4; ++kc) {
            int boff = ((ct0 + c) * 16 + l16) * 128 + kc * 32 + quad * 8;
            f.h[c][kc] = *(const short8*)(&Bh[boff]);
        }
}

__device__ __forceinline__ void gemm_ct2(const u16* As, const Bfrags& f, int l16, int quad,
                                         floatx4 (&acc)[4][2]) {
    #pragma unroll
    for (int kc = 0; kc < 4; ++kc) {
        short8 a[4];
        #pragma unroll
        for (int rt = 0; rt < 4; ++rt)
            a[rt] = *(const short8*)(&As[(rt * 16 + l16) * AS_STRIDE + kc * 32 + quad * 8]);
        #pragma unroll
        for (int rt = 0; rt < 4; ++rt)
            #pragma unroll
            for (int c = 0; c < 2; ++c)
                acc[rt][c] = __builtin_amdgcn_mfma_f32_16x16x32_bf16(a[rt], f.h[c][kc], acc[rt][c], 0, 0, 0);
    }
}

#define ZERO_ACC(acc) { _Pragma("unroll") for (int rt = 0; rt < 4; ++rt) \
    { acc[rt][0] = (floatx4){0.f,0.f,0.f,0.f}; acc[rt][1] = (floatx4){0.f,0.f,0.f,0.f}; } }

// gate panel (16x128, only col 0 nonzero) on wave 0; writes gate rows
__device__ __forceinline__ void gate_panel(const u16* As, const u16* __restrict__ Gh,
                                           const float* __restrict__ bg,
                                           float* __restrict__ gate,
                                           int m0, int M, int l16, int quad) {
    floatx4 gacc[4];
    #pragma unroll
    for (int rt = 0; rt < 4; ++rt) gacc[rt] = (floatx4){0.f, 0.f, 0.f, 0.f};
    #pragma unroll
    for (int kc = 0; kc < 4; ++kc) {
        int boff = l16 * 128 + kc * 32 + quad * 8;
        short8 gh = *(const short8*)(&Gh[boff]);
        #pragma unroll
        for (int rt = 0; rt < 4; ++rt) {
            short8 a = *(const short8*)(&As[(rt * 16 + l16) * AS_STRIDE + kc * 32 + quad * 8]);
            gacc[rt] = __builtin_amdgcn_mfma_f32_16x16x32_bf16(a, gh, gacc[rt], 0, 0, 0);
        }
    }
    if (l16 == 0) {
        float b0 = bg[0];
        #pragma unroll
        for (int rt = 0; rt < 4; ++rt)
            #pragma unroll
            for (int reg = 0; reg < 4; ++reg) {
                int row = m0 + rt * 16 + quad * 4 + reg;
                if (row < M) gate[row] = gacc[rt][reg] + b0;
            }
    }
}

// ---------------------------------------------------------------------------
// Layer-0 entry: ht(bf16) = x @ Wt + bt ; gate = x @ Wg + bg   (x is f32)
// ---------------------------------------------------------------------------
__global__ __launch_bounds__(256, 3) void gemm_gate_kernel(
    const float* __restrict__ Af,
    const u16* __restrict__ Gh, const float* __restrict__ bg,
    const u16* __restrict__ Bh, const float* __restrict__ bt,
    u16* __restrict__ ht, float* __restrict__ gate, int M) {
    __shared__ __align__(16) u16 As[64 * AS_STRIDE];
    const int t = threadIdx.x, m0 = blockIdx.x * 64;
    const int w = t >> 6, lane = t & 63, l16 = lane & 15, quad = lane >> 4, ct0 = w * 2;
    Bfrags f;
    load_B(Bh, ct0, l16, quad, f);      // in flight during staging
    stage_f32(Af, m0, M, As, t);
    __syncthreads();
    floatx4 acc[4][2];
    ZERO_ACC(acc);
    gemm_ct2(As, f, l16, quad, acc);
    if (w == 0) gate_panel(As, Gh, bg, gate, m0, M, l16, quad);
    #pragma unroll
    for (int c = 0; c < 2; ++c) {
        int cc = (ct0 + c) * 16 + l16;
        float b = bt[cc];
        #pragma unroll
        for (int rt = 0; rt < 4; ++rt)
            #pragma unroll
            for (int reg = 0; reg < 4; ++reg) {
                int row = m0 + rt * 16 + quad * 4 + reg;
                if (row < M) ht[(size_t)row * 128 + cc] = bf16_of(acc[rt][c][reg] + b);
            }
    }
}

// ---------------------------------------------------------------------------
// Attention aggregation: one wave per dst node; ht rows bf16; out packed bf16.
// Precomputed CSR-ordered weights (edge_w_kernel): only ONE dependent random
// load level remains (col -> ht row); w/col streams are sequential per node.
// ---------------------------------------------------------------------------
__global__ __launch_bounds__(256) void agg_kernel(const float* __restrict__ wcsr,
                                                  const u32* __restrict__ ht32,
                                                  const int* __restrict__ offs,
                                                  const int* __restrict__ col,
                                                  u32* __restrict__ aggb, int Nn) {
    int gt = blockIdx.x * 256 + threadIdx.x;
    int n = gt >> 6, lane = gt & 63;
    if (n >= Nn) return;
    int beg = offs[n], end = offs[n + 1];
    float denom0 = 1.0f, denom1 = 0.f;          // self: exp(gs-gs)=1
    u32 sv = ht32[(size_t)n * 64 + lane];
    float a0 = blo(sv), a1 = bhi(sv);
    float b0 = 0.f, b1 = 0.f;
    int e = beg;
    for (; e + 8 <= end; e += 8) {
        int c[8];
        #pragma unroll
        for (int j = 0; j < 8; ++j) c[j] = col[e + j];
        float wj[8];
        #pragma unroll
        for (int j = 0; j < 8; ++j) wj[j] = wcsr[e + j];
        u32 v[8];
        #pragma unroll
        for (int j = 0; j < 8; ++j) v[j] = ht32[(size_t)c[j] * 64 + lane];
        denom0 += (wj[0] + wj[1]) + (wj[2] + wj[3]);
        denom1 += (wj[4] + wj[5]) + (wj[6] + wj[7]);
        #pragma unroll
        for (int j = 0; j < 4; ++j) {
            a0 += wj[j] * blo(v[j]);
            a1 += wj[j] * bhi(v[j]);
        }
        #pragma unroll
        for (int j = 4; j < 8; ++j) {
            b0 += wj[j] * blo(v[j]);
            b1 += wj[j] * bhi(v[j]);
        }
    }
    for (; e < end; ++e) {
        int c = col[e];
        float w = wcsr[e];
        u32 v = ht32[(size_t)c * 64 + lane];
        denom0 += w;
        a0 += w * blo(v);
        a1 += w * bhi(v);
    }
    float inv = 1.0f / (denom0 + denom1);
    float r0 = (a0 + b0) * inv, r1 = (a1 + b1) * inv;
    aggb[(size_t)n * 64 + lane] = (u32)bf16_of(r0) | ((u32)bf16_of(r1) << 16);
}

// ---------------------------------------------------------------------------
// Mid-layer mega kernel: agg -> h (W1/BN/hswish, W2/hswish) -> next layer's
// ht = h @ Wt' + bt' and gate = h @ Wg' + bg'. h never touches global.
// ---------------------------------------------------------------------------
__global__ __launch_bounds__(256, 3) void layer_mid_kernel(
    const u16* __restrict__ A,
    const u16* __restrict__ B1h, const float* __restrict__ b1,
    const float* __restrict__ bng, const float* __restrict__ bnb,
    const float* __restrict__ bnm, const float* __restrict__ bnv,
    const u16* __restrict__ B2h, const float* __restrict__ b2,
    const u16* __restrict__ Wth, const float* __restrict__ bt,
    const u16* __restrict__ Gh, const float* __restrict__ bg,
    u16* __restrict__ htb, float* __restrict__ gate, int M) {
    __shared__ __align__(16) u16 As[64 * AS_STRIDE];
    __shared__ __align__(16) u16 Zs[64 * AS_STRIDE];
    const int t = threadIdx.x, m0 = blockIdx.x * 64;
    const int w = t >> 6, lane = t & 63, l16 = lane & 15, quad = lane >> 4, ct0 = w * 2;
    Bfrags f;
    load_B(B1h, ct0, l16, quad, f);     // in flight during staging
    stage_bf16(A, m0, M, As, t);
    __syncthreads();
    floatx4 acc[4][2];
    ZERO_ACC(acc);
    gemm_ct2(As, f, l16, quad, acc);
    // z = hswish(BN(acc+b1)) -> Zs
    #pragma unroll
    for (int c = 0; c < 2; ++c) {
        int cc = (ct0 + c) * 16 + l16;
        float sc = bng[cc] * rsqrtf(bnv[cc] + BN_EPS);
        float sh = bnb[cc] - bnm[cc] * sc;
        float bb = b1[cc];
        #pragma unroll
        for (int rt = 0; rt < 4; ++rt)
            #pragma unroll
            for (int reg = 0; reg < 4; ++reg) {
                int r = rt * 16 + quad * 4 + reg;
                Zs[r * AS_STRIDE + cc] = bf16_of(hswish((acc[rt][c][reg] + bb) * sc + sh));
            }
    }
    load_B(B2h, ct0, l16, quad, f);
    __syncthreads();            // Zs complete; As reads complete -> As reusable
    ZERO_ACC(acc);
    gemm_ct2(Zs, f, l16, quad, acc);
    // h = hswish(acc+b2) -> As (bf16)
    #pragma unroll
    for (int c = 0; c < 2; ++c) {
        int cc = (ct0 + c) * 16 + l16;
        float b = b2[cc];
        #pragma unroll
        for (int rt = 0; rt < 4; ++rt)
            #pragma unroll
            for (int reg = 0; reg < 4; ++reg) {
                int r = rt * 16 + quad * 4 + reg;
                As[r * AS_STRIDE + cc] = bf16_of(hswish(acc[rt][c][reg] + b));
            }
    }
    load_B(Wth, ct0, l16, quad, f);
    __syncthreads();            // h tile complete in As
    ZERO_ACC(acc);
    gemm_ct2(As, f, l16, quad, acc);
    if (w == 0) gate_panel(As, Gh, bg, gate, m0, M, l16, quad);
    #pragma unroll
    for (int c = 0; c < 2; ++c) {
        int cc = (ct0 + c) * 16 + l16;
        float b = bt[cc];
        #pragma unroll
        for (int rt = 0; rt < 4; ++rt)
            #pragma unroll
            for (int reg = 0; reg < 4; ++reg) {
                int row = m0 + rt * 16 + quad * 4 + reg;
                if (row < M) htb[(size_t)row * 128 + cc] = bf16_of(acc[rt][c][reg] + b);
            }
    }
}

// ---------------------------------------------------------------------------
// Final-layer mega kernel: agg -> h -> head: z' = hswish(h@Wp1+bp1),
// logits = z'@Wp2+bp2, out = log_softmax(logits).
// ---------------------------------------------------------------------------
__global__ __launch_bounds__(256, 3) void layer_final_kernel(
    const u16* __restrict__ A,
    const u16* __restrict__ B1h, const float* __restrict__ b1,
    const float* __restrict__ bng, const float* __restrict__ bnb,
    const float* __restrict__ bnm, const float* __restrict__ bnv,
    const u16* __restrict__ B2h, const float* __restrict__ b2,
    const u16* __restrict__ P1h, const float* __restrict__ bp1,
    const u16* __restrict__ P2h, const float* __restrict__ bp2,
    float* __restrict__ out, int M) {
    __shared__ __align__(16) u16 As[64 * AS_STRIDE];
    __shared__ __align__(16) u16 Zs[64 * AS_STRIDE];
    const int t = threadIdx.x, m0 = blockIdx.x * 64;
    const int w = t >> 6, lane = t & 63, l16 = lane & 15, quad = lane >> 4, ct0 = w * 2;
    Bfrags f;
    load_B(B1h, ct0, l16, quad, f);
    stage_bf16(A, m0, M, As, t);
    __syncthreads();
    floatx4 acc[4][2];
    ZERO_ACC(acc);
    gemm_ct2(As, f, l16, quad, acc);
    #pragma unroll
    for (int c = 0; c < 2; ++c) {
        int cc = (ct0 + c) * 16 + l16;
        float sc = bng[cc] * rsqrtf(bnv[cc] + BN_EPS);
        float sh = bnb[cc] - bnm[cc] * sc;
        float bb = b1[cc];
        #pragma unroll
        for (int rt = 0; rt < 4; ++rt)
            #pragma unroll
            for (int reg = 0; reg < 4; ++reg) {
                int r = rt * 16 + quad * 4 + reg;
                Zs[r * AS_STRIDE + cc] = bf16_of(hswish((acc[rt][c][reg] + bb) * sc + sh));
            }
    }
    load_B(B2h, ct0, l16, quad, f);
    __syncthreads();
    ZERO_ACC(acc);
    gemm_ct2(Zs, f, l16, quad, acc);
    // h = hswish(acc+b2) -> As
    #pragma unroll
    for (int c = 0; c < 2; ++c) {
        int cc = (ct0 + c) * 16 + l16;
        float b = b2[cc];
        #pragma unroll
        for (int rt = 0; rt < 4; ++rt)
            #pragma unroll
            for (int reg = 0; reg < 4; ++reg) {
                int r = rt * 16 + quad * 4 + reg;
                As[r * AS_STRIDE + cc] = bf16_of(hswish(acc[rt][c][reg] + b));
            }
    }
    load_B(P1h, ct0, l16, quad, f);
    __syncthreads();
    ZERO_ACC(acc);
    gemm_ct2(As, f, l16, quad, acc);
    // z' = hswish(acc+bp1) -> Zs
    #pragma unroll
    for (int c = 0; c < 2; ++c) {
        int cc = (ct0 + c) * 16 + l16;
        float bb = bp1[cc];
        #pragma unroll
        for (int rt = 0; rt < 4; ++rt)
            #pragma unroll
            for (int reg = 0; reg < 4; ++reg) {
                int r = rt * 16 + quad * 4 + reg;
                Zs[r * AS_STRIDE + cc] = bf16_of(hswish(acc[rt][c][reg] + bb));
            }
    }
    __syncthreads();
    // head GEMM2 row-split: wave w owns rows [16w,16w+16), all 3 col-tiles
    const int wr0 = w * 16;
    floatx4 acc2[3];
    #pragma unroll
    for (int ct = 0; ct < 3; ++ct) acc2[ct] = (floatx4){0.f, 0.f, 0.f, 0.f};
    #pragma unroll
    for (int kc = 0; kc < 4; ++kc) {
        short8 a = *(const short8*)(&Zs[(wr0 + l16) * AS_STRIDE + kc * 32 + quad * 8]);
        #pragma unroll
        for (int ct = 0; ct < 3; ++ct) {
            int boff = (ct * 16 + l16) * 128 + kc * 32 + quad * 8;
            short8 bh = *(const short8*)(&P2h[boff]);
            acc2[ct] = __builtin_amdgcn_mfma_f32_16x16x32_bf16(a, bh, acc2[ct], 0, 0, 0);
        }
    }
    #pragma unroll
    for (int reg = 0; reg < 4; ++reg) {
        float v[3];
        #pragma unroll
        for (int ct = 0; ct < 3; ++ct) {
            int c = ct * 16 + l16;
            v[ct] = (c < CLS) ? acc2[ct][reg] + bp2[c] : -INFINITY;
        }
        float mx = fmaxf(fmaxf(v[0], v[1]), v[2]);
        #pragma unroll
        for (int o = 1; o < 16; o <<= 1) mx = fmaxf(mx, __shfl_xor(mx, o));
        float s = 0.f;
        #pragma unroll
        for (int ct = 0; ct < 3; ++ct) s += (v[ct] > -INFINITY) ? __expf(v[ct] - mx) : 0.f;
        #pragma unroll
        for (int o = 1; o < 16; o <<= 1) s += __shfl_xor(s, o);
        float lse = mx + __logf(s);
        int row = m0 + wr0 + quad * 4 + reg;
        if (row < M) {
            #pragma unroll
            for (int ct = 0; ct < 3; ++ct) {
                int c = ct * 16 + l16;
                if (c < CLS) out[(size_t)row * CLS + c] = v[ct] - lse;
            }
        }
    }
}

// ---------------------------------------------------------------------------
extern "C" void kernel_launch(void* const* d_in, const int* in_sizes, int n_in,
                              void* d_out, int out_size, void* d_ws, size_t ws_size,
                              hipStream_t stream) {
    const float* x   = (const float*)d_in[0];
    const int*   src = (const int*)d_in[1];
    const int*   dst = (const int*)d_in[2];
    const float* Wg  = (const float*)d_in[3];
    const float* bg  = (const float*)d_in[4];
    const float* Wt  = (const float*)d_in[5];
    const float* bt  = (const float*)d_in[6];
    const float* W1  = (const float*)d_in[7];
    const float* b1  = (const float*)d_in[8];
    const float* bng = (const float*)d_in[9];
    const float* bnb = (const float*)d_in[10];
    const float* bnm = (const float*)d_in[11];
    const float* bnv = (const float*)d_in[12];
    const float* W2  = (const float*)d_in[13];
    const float* b2  = (const float*)d_in[14];
    const float* Wp1 = (const float*)d_in[15];
    const float* bp1 = (const float*)d_in[16];
    const float* Wp2 = (const float*)d_in[17];
    const float* bp2 = (const float*)d_in[18];
    float* out = (float*)d_out;

    const int N = in_sizes[0] / FD;
    const int E = in_sizes[1];
    const int L = in_sizes[3] / FD;
    const int nsq = 3 * L + 1;
    const int NB = (N + 255) / 256;
    const int EB = (E + 255) / 256;

    u16* htb    = (u16*)d_ws;                          // N*128 bf16
    u16* aggb   = htb + (size_t)N * FD;                // N*128 bf16 (packed u32/lane)
    float* gate = (float*)(aggb + (size_t)N * FD);     // N
    u16* wbuf   = (u16*)(gate + N);
    size_t wslots = (size_t)(nsq + 1) * 32768 + (size_t)L * 4096;
    int* counts = (int*)(wbuf + wslots);
    int* offs   = counts + N;
    int* rank   = offs + (N + 1);
    int* col    = rank + E;
    int* bsum   = col + E;
    float* wcsr = (float*)(bsum + NB + 1);

    // CSR build + weight prep (static inputs, ws re-poisoned each call)
    hipMemsetAsync(counts, 0, N * sizeof(int), stream);
    hist_kernel<<<EB, 256, 0, stream>>>(dst, counts, rank, E);
    prep_weights<<<dim3(64, nsq + 1 + L), 256, 0, stream>>>(Wt, W1, W2, Wp1, Wp2, Wg, wbuf, L);
    scan_p1<<<NB, 256, 0, stream>>>(counts, bsum, N);
    scan_p2<<<1, 256, 0, stream>>>(bsum, NB, offs, N);
    scan_p3<<<NB, 256, 0, stream>>>(counts, bsum, offs, N);
    scatter_kernel<<<EB, 256, 0, stream>>>(src, dst, offs, rank, col, E);

    const int grid_g = (N + 63) / 64;
    const int wave_grid = (N + 3) / 4;

    u16* gp0 = wbuf + (size_t)(nsq + 1) * 32768;
    u16* wt0 = wbuf;
    gemm_gate_kernel<<<grid_g, 256, 0, stream>>>(x, gp0, bg, wt0, bt, htb, gate, N);
    for (int i = 0; i < L; ++i) {
        edge_w_kernel<<<EB, 256, 0, stream>>>(src, dst, offs, rank, gate, wcsr, E);
        agg_kernel<<<wave_grid, 256, 0, stream>>>(wcsr, (const u32*)htb,
                                                  offs, col, (u32*)aggb, N);
        u16* w1 = wbuf + (size_t)(L + i) * 32768;
        u16* w2 = wbuf + (size_t)(2 * L + i) * 32768;
        if (i < L - 1) {
            u16* wtn = wbuf + (size_t)(i + 1) * 32768;
            u16* gpn = wbuf + (size_t)(nsq + 1) * 32768 + (size_t)(i + 1) * 4096;
            layer_mid_kernel<<<grid_g, 256, 0, stream>>>(aggb,
                w1, b1 + i * FD,
                bng + i * FD, bnb + i * FD, bnm + i * FD, bnv + i * FD,
                w2, b2 + i * FD,
                wtn, bt + (i + 1) * FD,
                gpn, bg + (i + 1),
                htb, gate, N);
        } else {
            u16* wp1 = wbuf + (size_t)(3 * L) * 32768;
            u16* wp2 = wbuf + (size_t)nsq * 32768;
            layer_final_kernel<<<grid_g, 256, 0, stream>>>(aggb,
                w1, b1 + i * FD,
                bng + i * FD, bnb + i * FD, bnm + i * FD, bnv + i * FD,
                w2, b2 + i * FD,
                wp1, bp1,
                wp2, bp2,
                out, N);
        }
    }
}

// Round 13
// 422.218 us; speedup vs baseline: 1.1283x; 1.1216x over previous
//
#include <hip/hip_runtime.h>
#include <math.h>

#define FD 128
#define CLS 40
#define BN_EPS 1e-5f
#define AS_STRIDE 136   // ushort stride: 272 B rows, 16B-aligned, 2-way bank aliasing only
// R13 = revert to R10 (best: 421 us). Lessons: R11 fused-agg serialized the
// gather (regressed); R12 per-layer edge_w scatter-write cost ~20us/layer
// (regressed). Standalone agg + single rank-scatter CSR is the sweet spot.

typedef short short8 __attribute__((ext_vector_type(8)));
typedef float floatx4 __attribute__((ext_vector_type(4)));
typedef unsigned short ushort4v __attribute__((ext_vector_type(4)));
typedef unsigned short u16;
typedef unsigned int u32;

__device__ __forceinline__ u16 bf16_of(float v) {
    unsigned int u = __float_as_uint(v);
    unsigned int r = u + 0x7FFFu + ((u >> 16) & 1u);   // RNE
    return (u16)(r >> 16);
}
__device__ __forceinline__ float bf16f(u16 h) {
    return __uint_as_float(((unsigned int)h) << 16);
}
__device__ __forceinline__ float blo(u32 v) { return __uint_as_float(v << 16); }
__device__ __forceinline__ float bhi(u32 v) { return __uint_as_float(v & 0xFFFF0000u); }
__device__ __forceinline__ float hswish(float x) {
    return x * fminf(fmaxf(x + 3.0f, 0.0f), 6.0f) * (1.0f / 6.0f);
}

// ---------------------------------------------------------------------------
// CSR build: hist(+rank) -> 3-pass parallel exclusive scan -> rank-scatter
// ---------------------------------------------------------------------------
__global__ void hist_kernel(const int* __restrict__ dst, int* __restrict__ cnt,
                            int* __restrict__ rank, int E) {
    int e = blockIdx.x * 256 + threadIdx.x;
    if (e < E) rank[e] = atomicAdd(&cnt[dst[e]], 1);
}

__global__ __launch_bounds__(256) void scan_p1(const int* __restrict__ cnt,
                                               int* __restrict__ bsum, int Nn) {
    const int t = threadIdx.x, b = blockIdx.x;
    int i = b * 256 + t;
    int v = (i < Nn) ? cnt[i] : 0;
    #pragma unroll
    for (int o = 32; o; o >>= 1) v += __shfl_xor(v, o);
    __shared__ int ws[4];
    if ((t & 63) == 0) ws[t >> 6] = v;
    __syncthreads();
    if (t == 0) bsum[b] = ws[0] + ws[1] + ws[2] + ws[3];
}

__global__ __launch_bounds__(256) void scan_p2(int* __restrict__ bsum, int NB,
                                               int* __restrict__ offs, int Nn) {
    __shared__ int wsum[4];
    __shared__ int run_s;
    const int t = threadIdx.x, lane = t & 63, wid = t >> 6;
    if (t == 0) run_s = 0;
    __syncthreads();
    for (int base = 0; base < NB; base += 256) {
        int i = base + t;
        int v = (i < NB) ? bsum[i] : 0;
        int x = v;
        #pragma unroll
        for (int o = 1; o < 64; o <<= 1) {
            int y = __shfl_up(x, o);
            if (lane >= o) x += y;
        }
        if (lane == 63) wsum[wid] = x;
        __syncthreads();
        int pre = run_s;
        #pragma unroll
        for (int w = 0; w < 4; ++w) { if (w < wid) pre += wsum[w]; }
        if (i < NB) bsum[i] = pre + x - v;
        __syncthreads();
        if (t == 0) run_s += wsum[0] + wsum[1] + wsum[2] + wsum[3];
        __syncthreads();
    }
    if (t == 0) offs[Nn] = run_s;
}

__global__ __launch_bounds__(256) void scan_p3(const int* __restrict__ cnt,
                                               const int* __restrict__ bsum,
                                               int* __restrict__ offs, int Nn) {
    __shared__ int wsum[4];
    const int t = threadIdx.x, b = blockIdx.x, lane = t & 63, wid = t >> 6;
    int i = b * 256 + t;
    int v = (i < Nn) ? cnt[i] : 0;
    int x = v;
    #pragma unroll
    for (int o = 1; o < 64; o <<= 1) {
        int y = __shfl_up(x, o);
        if (lane >= o) x += y;
    }
    if (lane == 63) wsum[wid] = x;
    __syncthreads();
    int pre = bsum[b];
    #pragma unroll
    for (int w = 0; w < 4; ++w) { if (w < wid) pre += wsum[w]; }
    if (i < Nn) offs[i] = pre + x - v;
}

__global__ void scatter_kernel(const int* __restrict__ src, const int* __restrict__ dst,
                               const int* __restrict__ offs, const int* __restrict__ rank,
                               int* __restrict__ col, int E) {
    int e = blockIdx.x * 256 + threadIdx.x;
    if (e < E) col[offs[dst[e]] + rank[e]] = src[e];
}

// ---------------------------------------------------------------------------
// Weight prep: square W[k][n] -> bf16 transposed [n][k] (32768-short slots,
// hi only). Wp2 padded [48][128]. Wg panels [16][128].
// ---------------------------------------------------------------------------
__global__ void prep_weights(const float* __restrict__ Wt, const float* __restrict__ W1,
                             const float* __restrict__ W2, const float* __restrict__ Wp1,
                             const float* __restrict__ Wp2, const float* __restrict__ Wg,
                             u16* __restrict__ wbuf, int L) {
    const int m = blockIdx.y;
    const int id = blockIdx.x * 256 + threadIdx.x;
    const int nsq = 3 * L + 1;
    if (m < nsq) {
        u16* base = wbuf + (size_t)m * 32768;
        const float* src = (m < L) ? Wt + m * 16384
                         : (m < 2 * L) ? W1 + (m - L) * 16384
                         : (m < 3 * L) ? W2 + (m - 2 * L) * 16384
                         : Wp1;
        int n = id >> 7, k = id & 127;
        base[n * 128 + k] = bf16_of(src[k * 128 + n]);
    } else if (m == nsq) {               // Wp2
        if (id >= 48 * 128) return;
        u16* base = wbuf + (size_t)m * 32768;
        int n = id >> 7, k = id & 127;
        base[n * 128 + k] = bf16_of((n < CLS) ? Wp2[k * CLS + n] : 0.f);
    } else {                             // Wg panel
        int gi = m - (nsq + 1);
        if (id >= 2048) return;
        u16* base = wbuf + (size_t)(nsq + 1) * 32768 + (size_t)gi * 4096;
        base[id] = bf16_of((id < 128) ? Wg[gi * 128 + id] : 0.f);
    }
}

// ---------------------------------------------------------------------------
// GEMM building blocks. Block tile 64 rows x 128 cols, K=128, 4 waves.
// COLUMN-split: wave w owns cols [32w, 32w+32); 8 single-bf16 B-fragments in
// registers for the whole GEMM -> 8 MFMAs per B-load, no re-fetch.
// ---------------------------------------------------------------------------
__device__ __forceinline__ void stage_f32(const float* __restrict__ A, int m0, int M,
                                          u16* As, int t) {
    #pragma unroll
    for (int i = 0; i < 8; ++i) {
        int id = i * 256 + t;
        int row = id >> 5, c4 = id & 31;
        float4 v = make_float4(0.f, 0.f, 0.f, 0.f);
        if (m0 + row < M) v = ((const float4*)A)[(size_t)(m0 + row) * 32 + c4];
        ushort4v hh = {bf16_of(v.x), bf16_of(v.y), bf16_of(v.z), bf16_of(v.w)};
        *(ushort4v*)(&As[row * AS_STRIDE + c4 * 4]) = hh;
    }
}

__device__ __forceinline__ void stage_bf16(const u16* __restrict__ A, int m0, int M,
                                           u16* As, int t) {
    #pragma unroll
    for (int i = 0; i < 4; ++i) {
        int id = i * 256 + t;
        int row = id >> 4, c8 = id & 15;
        short8 v = {0, 0, 0, 0, 0, 0, 0, 0};
        if (m0 + row < M) v = ((const short8*)A)[(size_t)(m0 + row) * 16 + c8];
        *(short8*)(&As[row * AS_STRIDE + c8 * 8]) = v;
    }
}

struct Bfrags { short8 h[2][4]; };   // [ct][kc], 32 VGPRs (single bf16)

__device__ __forceinline__ void load_B(const u16* __restrict__ Bh,
                                       int ct0, int l16, int quad, Bfrags& f) {
    #pragma unroll
    for (int c = 0; c < 2; ++c)
        #pragma unroll
        for (int kc = 0; kc < 4; ++kc) {
            int boff = ((ct0 + c) * 16 + l16) * 128 + kc * 32 + quad * 8;
            f.h[c][kc] = *(const short8*)(&Bh[boff]);
        }
}

__device__ __forceinline__ void gemm_ct2(const u16* As, const Bfrags& f, int l16, int quad,
                                         floatx4 (&acc)[4][2]) {
    #pragma unroll
    for (int kc = 0; kc < 4; ++kc) {
        short8 a[4];
        #pragma unroll
        for (int rt = 0; rt < 4; ++rt)
            a[rt] = *(const short8*)(&As[(rt * 16 + l16) * AS_STRIDE + kc * 32 + quad * 8]);
        #pragma unroll
        for (int rt = 0; rt < 4; ++rt)
            #pragma unroll
            for (int c = 0; c < 2; ++c)
                acc[rt][c] = __builtin_amdgcn_mfma_f32_16x16x32_bf16(a[rt], f.h[c][kc], acc[rt][c], 0, 0, 0);
    }
}

#define ZERO_ACC(acc) { _Pragma("unroll") for (int rt = 0; rt < 4; ++rt) \
    { acc[rt][0] = (floatx4){0.f,0.f,0.f,0.f}; acc[rt][1] = (floatx4){0.f,0.f,0.f,0.f}; } }

// gate panel (16x128, only col 0 nonzero) on wave 0; writes gate rows
__device__ __forceinline__ void gate_panel(const u16* As, const u16* __restrict__ Gh,
                                           const float* __restrict__ bg,
                                           float* __restrict__ gate,
                                           int m0, int M, int l16, int quad) {
    floatx4 gacc[4];
    #pragma unroll
    for (int rt = 0; rt < 4; ++rt) gacc[rt] = (floatx4){0.f, 0.f, 0.f, 0.f};
    #pragma unroll
    for (int kc = 0; kc < 4; ++kc) {
        int boff = l16 * 128 + kc * 32 + quad * 8;
        short8 gh = *(const short8*)(&Gh[boff]);
        #pragma unroll
        for (int rt = 0; rt < 4; ++rt) {
            short8 a = *(const short8*)(&As[(rt * 16 + l16) * AS_STRIDE + kc * 32 + quad * 8]);
            gacc[rt] = __builtin_amdgcn_mfma_f32_16x16x32_bf16(a, gh, gacc[rt], 0, 0, 0);
        }
    }
    if (l16 == 0) {
        float b0 = bg[0];
        #pragma unroll
        for (int rt = 0; rt < 4; ++rt)
            #pragma unroll
            for (int reg = 0; reg < 4; ++reg) {
                int row = m0 + rt * 16 + quad * 4 + reg;
                if (row < M) gate[row] = gacc[rt][reg] + b0;
            }
    }
}

// ---------------------------------------------------------------------------
// Layer-0 entry: ht(bf16) = x @ Wt + bt ; gate = x @ Wg + bg   (x is f32)
// ---------------------------------------------------------------------------
__global__ __launch_bounds__(256, 3) void gemm_gate_kernel(
    const float* __restrict__ Af,
    const u16* __restrict__ Gh, const float* __restrict__ bg,
    const u16* __restrict__ Bh, const float* __restrict__ bt,
    u16* __restrict__ ht, float* __restrict__ gate, int M) {
    __shared__ __align__(16) u16 As[64 * AS_STRIDE];
    const int t = threadIdx.x, m0 = blockIdx.x * 64;
    const int w = t >> 6, lane = t & 63, l16 = lane & 15, quad = lane >> 4, ct0 = w * 2;
    Bfrags f;
    load_B(Bh, ct0, l16, quad, f);      // in flight during staging
    stage_f32(Af, m0, M, As, t);
    __syncthreads();
    floatx4 acc[4][2];
    ZERO_ACC(acc);
    gemm_ct2(As, f, l16, quad, acc);
    if (w == 0) gate_panel(As, Gh, bg, gate, m0, M, l16, quad);
    #pragma unroll
    for (int c = 0; c < 2; ++c) {
        int cc = (ct0 + c) * 16 + l16;
        float b = bt[cc];
        #pragma unroll
        for (int rt = 0; rt < 4; ++rt)
            #pragma unroll
            for (int reg = 0; reg < 4; ++reg) {
                int row = m0 + rt * 16 + quad * 4 + reg;
                if (row < M) ht[(size_t)row * 128 + cc] = bf16_of(acc[rt][c][reg] + b);
            }
    }
}

// ---------------------------------------------------------------------------
// Attention aggregation: one wave per dst node; ht rows bf16; out packed bf16.
// Max-free softmax shifted by the SELF gate gs (shift-invariant; |g-gs|<<88).
// Edge loop unrolled x8 for memory-level parallelism. Gate gathers are
// L2-resident (200 KB); the 512B ht-row gathers are the floor.
// ---------------------------------------------------------------------------
__global__ __launch_bounds__(256) void agg_kernel(const float* __restrict__ gate,
                                                  const u32* __restrict__ ht32,
                                                  const int* __restrict__ offs,
                                                  const int* __restrict__ col,
                                                  u32* __restrict__ aggb, int Nn) {
    int gt = blockIdx.x * 256 + threadIdx.x;
    int n = gt >> 6, lane = gt & 63;
    if (n >= Nn) return;
    int beg = offs[n], end = offs[n + 1];
    float gs = gate[n];
    float denom0 = 1.0f, denom1 = 0.f;          // self: exp(gs-gs)=1
    u32 sv = ht32[(size_t)n * 64 + lane];
    float a0 = blo(sv), a1 = bhi(sv);
    float b0 = 0.f, b1 = 0.f;
    int e = beg;
    for (; e + 8 <= end; e += 8) {
        int c[8];
        #pragma unroll
        for (int j = 0; j < 8; ++j) c[j] = col[e + j];
        float g[8];
        #pragma unroll
        for (int j = 0; j < 8; ++j) g[j] = gate[c[j]];
        u32 v[8];
        #pragma unroll
        for (int j = 0; j < 8; ++j) v[j] = ht32[(size_t)c[j] * 64 + lane];
        float wj[8];
        #pragma unroll
        for (int j = 0; j < 8; ++j) wj[j] = __expf(g[j] - gs);
        denom0 += (wj[0] + wj[1]) + (wj[2] + wj[3]);
        denom1 += (wj[4] + wj[5]) + (wj[6] + wj[7]);
        #pragma unroll
        for (int j = 0; j < 4; ++j) {
            a0 += wj[j] * blo(v[j]);
            a1 += wj[j] * bhi(v[j]);
        }
        #pragma unroll
        for (int j = 4; j < 8; ++j) {
            b0 += wj[j] * blo(v[j]);
            b1 += wj[j] * bhi(v[j]);
        }
    }
    for (; e < end; ++e) {
        int c = col[e];
        float w = __expf(gate[c] - gs);
        u32 v = ht32[(size_t)c * 64 + lane];
        denom0 += w;
        a0 += w * blo(v);
        a1 += w * bhi(v);
    }
    float inv = 1.0f / (denom0 + denom1);
    float r0 = (a0 + b0) * inv, r1 = (a1 + b1) * inv;
    aggb[(size_t)n * 64 + lane] = (u32)bf16_of(r0) | ((u32)bf16_of(r1) << 16);
}

// ---------------------------------------------------------------------------
// Mid-layer mega kernel: agg -> h (W1/BN/hswish, W2/hswish) -> next layer's
// ht = h @ Wt' + bt' and gate = h @ Wg' + bg'. h never touches global.
// ---------------------------------------------------------------------------
__global__ __launch_bounds__(256, 3) void layer_mid_kernel(
    const u16* __restrict__ A,
    const u16* __restrict__ B1h, const float* __restrict__ b1,
    const float* __restrict__ bng, const float* __restrict__ bnb,
    const float* __restrict__ bnm, const float* __restrict__ bnv,
    const u16* __restrict__ B2h, const float* __restrict__ b2,
    const u16* __restrict__ Wth, const float* __restrict__ bt,
    const u16* __restrict__ Gh, const float* __restrict__ bg,
    u16* __restrict__ htb, float* __restrict__ gate, int M) {
    __shared__ __align__(16) u16 As[64 * AS_STRIDE];
    __shared__ __align__(16) u16 Zs[64 * AS_STRIDE];
    const int t = threadIdx.x, m0 = blockIdx.x * 64;
    const int w = t >> 6, lane = t & 63, l16 = lane & 15, quad = lane >> 4, ct0 = w * 2;
    Bfrags f;
    load_B(B1h, ct0, l16, quad, f);     // in flight during staging
    stage_bf16(A, m0, M, As, t);
    __syncthreads();
    floatx4 acc[4][2];
    ZERO_ACC(acc);
    gemm_ct2(As, f, l16, quad, acc);
    // z = hswish(BN(acc+b1)) -> Zs
    #pragma unroll
    for (int c = 0; c < 2; ++c) {
        int cc = (ct0 + c) * 16 + l16;
        float sc = bng[cc] * rsqrtf(bnv[cc] + BN_EPS);
        float sh = bnb[cc] - bnm[cc] * sc;
        float bb = b1[cc];
        #pragma unroll
        for (int rt = 0; rt < 4; ++rt)
            #pragma unroll
            for (int reg = 0; reg < 4; ++reg) {
                int r = rt * 16 + quad * 4 + reg;
                Zs[r * AS_STRIDE + cc] = bf16_of(hswish((acc[rt][c][reg] + bb) * sc + sh));
            }
    }
    load_B(B2h, ct0, l16, quad, f);
    __syncthreads();            // Zs complete; As reads complete -> As reusable
    ZERO_ACC(acc);
    gemm_ct2(Zs, f, l16, quad, acc);
    // h = hswish(acc+b2) -> As (bf16)
    #pragma unroll
    for (int c = 0; c < 2; ++c) {
        int cc = (ct0 + c) * 16 + l16;
        float b = b2[cc];
        #pragma unroll
        for (int rt = 0; rt < 4; ++rt)
            #pragma unroll
            for (int reg = 0; reg < 4; ++reg) {
                int r = rt * 16 + quad * 4 + reg;
                As[r * AS_STRIDE + cc] = bf16_of(hswish(acc[rt][c][reg] + b));
            }
    }
    load_B(Wth, ct0, l16, quad, f);
    __syncthreads();            // h tile complete in As
    ZERO_ACC(acc);
    gemm_ct2(As, f, l16, quad, acc);
    if (w == 0) gate_panel(As, Gh, bg, gate, m0, M, l16, quad);
    #pragma unroll
    for (int c = 0; c < 2; ++c) {
        int cc = (ct0 + c) * 16 + l16;
        float b = bt[cc];
        #pragma unroll
        for (int rt = 0; rt < 4; ++rt)
            #pragma unroll
            for (int reg = 0; reg < 4; ++reg) {
                int row = m0 + rt * 16 + quad * 4 + reg;
                if (row < M) htb[(size_t)row * 128 + cc] = bf16_of(acc[rt][c][reg] + b);
            }
    }
}

// ---------------------------------------------------------------------------
// Final-layer mega kernel: agg -> h -> head: z' = hswish(h@Wp1+bp1),
// logits = z'@Wp2+bp2, out = log_softmax(logits).
// ---------------------------------------------------------------------------
__global__ __launch_bounds__(256, 3) void layer_final_kernel(
    const u16* __restrict__ A,
    const u16* __restrict__ B1h, const float* __restrict__ b1,
    const float* __restrict__ bng, const float* __restrict__ bnb,
    const float* __restrict__ bnm, const float* __restrict__ bnv,
    const u16* __restrict__ B2h, const float* __restrict__ b2,
    const u16* __restrict__ P1h, const float* __restrict__ bp1,
    const u16* __restrict__ P2h, const float* __restrict__ bp2,
    float* __restrict__ out, int M) {
    __shared__ __align__(16) u16 As[64 * AS_STRIDE];
    __shared__ __align__(16) u16 Zs[64 * AS_STRIDE];
    const int t = threadIdx.x, m0 = blockIdx.x * 64;
    const int w = t >> 6, lane = t & 63, l16 = lane & 15, quad = lane >> 4, ct0 = w * 2;
    Bfrags f;
    load_B(B1h, ct0, l16, quad, f);
    stage_bf16(A, m0, M, As, t);
    __syncthreads();
    floatx4 acc[4][2];
    ZERO_ACC(acc);
    gemm_ct2(As, f, l16, quad, acc);
    #pragma unroll
    for (int c = 0; c < 2; ++c) {
        int cc = (ct0 + c) * 16 + l16;
        float sc = bng[cc] * rsqrtf(bnv[cc] + BN_EPS);
        float sh = bnb[cc] - bnm[cc] * sc;
        float bb = b1[cc];
        #pragma unroll
        for (int rt = 0; rt < 4; ++rt)
            #pragma unroll
            for (int reg = 0; reg < 4; ++reg) {
                int r = rt * 16 + quad * 4 + reg;
                Zs[r * AS_STRIDE + cc] = bf16_of(hswish((acc[rt][c][reg] + bb) * sc + sh));
            }
    }
    load_B(B2h, ct0, l16, quad, f);
    __syncthreads();
    ZERO_ACC(acc);
    gemm_ct2(Zs, f, l16, quad, acc);
    // h = hswish(acc+b2) -> As
    #pragma unroll
    for (int c = 0; c < 2; ++c) {
        int cc = (ct0 + c) * 16 + l16;
        float b = b2[cc];
        #pragma unroll
        for (int rt = 0; rt < 4; ++rt)
            #pragma unroll
            for (int reg = 0; reg < 4; ++reg) {
                int r = rt * 16 + quad * 4 + reg;
                As[r * AS_STRIDE + cc] = bf16_of(hswish(acc[rt][c][reg] + b));
            }
    }
    load_B(P1h, ct0, l16, quad, f);
    __syncthreads();
    ZERO_ACC(acc);
    gemm_ct2(As, f, l16, quad, acc);
    // z' = hswish(acc+bp1) -> Zs
    #pragma unroll
    for (int c = 0; c < 2; ++c) {
        int cc = (ct0 + c) * 16 + l16;
        float bb = bp1[cc];
        #pragma unroll
        for (int rt = 0; rt < 4; ++rt)
            #pragma unroll
            for (int reg = 0; reg < 4; ++reg) {
                int r = rt * 16 + quad * 4 + reg;
                Zs[r * AS_STRIDE + cc] = bf16_of(hswish(acc[rt][c][reg] + bb));
            }
    }
    __syncthreads();
    // head GEMM2 row-split: wave w owns rows [16w,16w+16), all 3 col-tiles
    const int wr0 = w * 16;
    floatx4 acc2[3];
    #pragma unroll
    for (int ct = 0; ct < 3; ++ct) acc2[ct] = (floatx4){0.f, 0.f, 0.f, 0.f};
    #pragma unroll
    for (int kc = 0; kc < 4; ++kc) {
        short8 a = *(const short8*)(&Zs[(wr0 + l16) * AS_STRIDE + kc * 32 + quad * 8]);
        #pragma unroll
        for (int ct = 0; ct < 3; ++ct) {
            int boff = (ct * 16 + l16) * 128 + kc * 32 + quad * 8;
            short8 bh = *(const short8*)(&P2h[boff]);
            acc2[ct] = __builtin_amdgcn_mfma_f32_16x16x32_bf16(a, bh, acc2[ct], 0, 0, 0);
        }
    }
    #pragma unroll
    for (int reg = 0; reg < 4; ++reg) {
        float v[3];
        #pragma unroll
        for (int ct = 0; ct < 3; ++ct) {
            int c = ct * 16 + l16;
            v[ct] = (c < CLS) ? acc2[ct][reg] + bp2[c] : -INFINITY;
        }
        float mx = fmaxf(fmaxf(v[0], v[1]), v[2]);
        #pragma unroll
        for (int o = 1; o < 16; o <<= 1) mx = fmaxf(mx, __shfl_xor(mx, o));
        float s = 0.f;
        #pragma unroll
        for (int ct = 0; ct < 3; ++ct) s += (v[ct] > -INFINITY) ? __expf(v[ct] - mx) : 0.f;
        #pragma unroll
        for (int o = 1; o < 16; o <<= 1) s += __shfl_xor(s, o);
        float lse = mx + __logf(s);
        int row = m0 + wr0 + quad * 4 + reg;
        if (row < M) {
            #pragma unroll
            for (int ct = 0; ct < 3; ++ct) {
                int c = ct * 16 + l16;
                if (c < CLS) out[(size_t)row * CLS + c] = v[ct] - lse;
            }
        }
    }
}

// ---------------------------------------------------------------------------
extern "C" void kernel_launch(void* const* d_in, const int* in_sizes, int n_in,
                              void* d_out, int out_size, void* d_ws, size_t ws_size,
                              hipStream_t stream) {
    const float* x   = (const float*)d_in[0];
    const int*   src = (const int*)d_in[1];
    const int*   dst = (const int*)d_in[2];
    const float* Wg  = (const float*)d_in[3];
    const float* bg  = (const float*)d_in[4];
    const float* Wt  = (const float*)d_in[5];
    const float* bt  = (const float*)d_in[6];
    const float* W1  = (const float*)d_in[7];
    const float* b1  = (const float*)d_in[8];
    const float* bng = (const float*)d_in[9];
    const float* bnb = (const float*)d_in[10];
    const float* bnm = (const float*)d_in[11];
    const float* bnv = (const float*)d_in[12];
    const float* W2  = (const float*)d_in[13];
    const float* b2  = (const float*)d_in[14];
    const float* Wp1 = (const float*)d_in[15];
    const float* bp1 = (const float*)d_in[16];
    const float* Wp2 = (const float*)d_in[17];
    const float* bp2 = (const float*)d_in[18];
    float* out = (float*)d_out;

    const int N = in_sizes[0] / FD;
    const int E = in_sizes[1];
    const int L = in_sizes[3] / FD;
    const int nsq = 3 * L + 1;
    const int NB = (N + 255) / 256;
    const int EB = (E + 255) / 256;

    u16* htb    = (u16*)d_ws;                          // N*128 bf16
    u16* aggb   = htb + (size_t)N * FD;                // N*128 bf16 (packed u32/lane)
    float* gate = (float*)(aggb + (size_t)N * FD);     // N
    u16* wbuf   = (u16*)(gate + N);
    size_t wslots = (size_t)(nsq + 1) * 32768 + (size_t)L * 4096;
    int* counts = (int*)(wbuf + wslots);
    int* offs   = counts + N;
    int* rank   = offs + (N + 1);
    int* col    = rank + E;
    int* bsum   = col + E;

    // CSR build + weight prep (static inputs, ws re-poisoned each call)
    hipMemsetAsync(counts, 0, N * sizeof(int), stream);
    hist_kernel<<<EB, 256, 0, stream>>>(dst, counts, rank, E);
    prep_weights<<<dim3(64, nsq + 1 + L), 256, 0, stream>>>(Wt, W1, W2, Wp1, Wp2, Wg, wbuf, L);
    scan_p1<<<NB, 256, 0, stream>>>(counts, bsum, N);
    scan_p2<<<1, 256, 0, stream>>>(bsum, NB, offs, N);
    scan_p3<<<NB, 256, 0, stream>>>(counts, bsum, offs, N);
    scatter_kernel<<<EB, 256, 0, stream>>>(src, dst, offs, rank, col, E);

    const int grid_g = (N + 63) / 64;
    const int wave_grid = (N + 3) / 4;

    u16* gp0 = wbuf + (size_t)(nsq + 1) * 32768;
    u16* wt0 = wbuf;
    gemm_gate_kernel<<<grid_g, 256, 0, stream>>>(x, gp0, bg, wt0, bt, htb, gate, N);
    for (int i = 0; i < L; ++i) {
        agg_kernel<<<wave_grid, 256, 0, stream>>>(gate, (const u32*)htb,
                                                  offs, col, (u32*)aggb, N);
        u16* w1 = wbuf + (size_t)(L + i) * 32768;
        u16* w2 = wbuf + (size_t)(2 * L + i) * 32768;
        if (i < L - 1) {
            u16* wtn = wbuf + (size_t)(i + 1) * 32768;
            u16* gpn = wbuf + (size_t)(nsq + 1) * 32768 + (size_t)(i + 1) * 4096;
            layer_mid_kernel<<<grid_g, 256, 0, stream>>>(aggb,
                w1, b1 + i * FD,
                bng + i * FD, bnb + i * FD, bnm + i * FD, bnv + i * FD,
                w2, b2 + i * FD,
                wtn, bt + (i + 1) * FD,
                gpn, bg + (i + 1),
                htb, gate, N);
        } else {
            u16* wp1 = wbuf + (size_t)(3 * L) * 32768;
            u16* wp2 = wbuf + (size_t)nsq * 32768;
            layer_final_kernel<<<grid_g, 256, 0, stream>>>(aggb,
                w1, b1 + i * FD,
                bng + i * FD, bnb + i * FD, bnm + i * FD, bnv + i * FD,
                w2, b2 + i * FD,
                wp1, bp1,
                wp2, bp2,
                out, N);
        }
    }
}